// Round 1
// baseline (1117.637 us; speedup 1.0000x reference)
//
#include <hip/hip_runtime.h>
#include <stdint.h>

typedef __attribute__((ext_vector_type(8))) short short8;
typedef __attribute__((ext_vector_type(4))) float f32x4;

__device__ __forceinline__ float bf2f(unsigned short s) {
  return __uint_as_float(((unsigned)s) << 16);
}
__device__ __forceinline__ unsigned short f2bf(float f) {
  unsigned u = __float_as_uint(f);
  u += 0x7fffu + ((u >> 16) & 1u);   // round-to-nearest-even
  return (unsigned short)(u >> 16);
}

// ---------------- CSR build ----------------
__global__ void gs_zero_i32(int* p, int n) {
  int i = blockIdx.x * 256 + threadIdx.x;
  if (i < n) p[i] = 0;
}

__global__ void gs_count_deg(const int* __restrict__ dst, int* __restrict__ cnt, int E) {
  int e = blockIdx.x * 256 + threadIdx.x;
  if (e < E) atomicAdd(&cnt[dst[e]], 1);
}

__global__ void gs_scan_csr(const int* __restrict__ cnt, int* __restrict__ rp,
                            int* __restrict__ cur, int n) {
  __shared__ int sm[1024];
  __shared__ int carry_s;
  if (threadIdx.x == 0) carry_s = 0;
  __syncthreads();
  for (int base = 0; base < n; base += 1024) {
    int i = base + (int)threadIdx.x;
    int v = (i < n) ? cnt[i] : 0;
    sm[threadIdx.x] = v;
    __syncthreads();
    for (int off = 1; off < 1024; off <<= 1) {
      int t = (threadIdx.x >= (unsigned)off) ? sm[threadIdx.x - off] : 0;
      __syncthreads();
      sm[threadIdx.x] += t;
      __syncthreads();
    }
    int incl = sm[threadIdx.x];
    int excl = carry_s + incl - v;
    if (i < n) { rp[i] = excl; cur[i] = excl; }
    __syncthreads();
    if (threadIdx.x == 1023) carry_s += sm[1023];
    __syncthreads();
  }
  if (threadIdx.x == 0) rp[n] = carry_s;
}

__global__ void gs_fill_csr(const int* __restrict__ src, const int* __restrict__ dst,
                            int* __restrict__ cur, int* __restrict__ col, int E) {
  int e = blockIdx.x * 256 + threadIdx.x;
  if (e < E) {
    int pos = atomicAdd(&cur[dst[e]], 1);
    col[pos] = src[e];
  }
}

// ---------------- conversions ----------------
__global__ void gs_f32_to_bf16(const float* __restrict__ in, unsigned short* __restrict__ out, int n4) {
  int i = blockIdx.x * 256 + threadIdx.x;
  if (i < n4) {
    float4 f = ((const float4*)in)[i];
    ushort4 o;
    o.x = f2bf(f.x); o.y = f2bf(f.y); o.z = f2bf(f.z); o.w = f2bf(f.w);
    ((ushort4*)out)[i] = o;
  }
}

// W [K x Nn] fp32 row-major  ->  WT [Nn x K] bf16 row-major (B^T layout)
__global__ void gs_pack_wt(const float* __restrict__ W, unsigned short* __restrict__ WT,
                           int K, int Nn) {
  int idx = blockIdx.x * 256 + threadIdx.x;
  if (idx >= K * Nn) return;
  int n = idx / K;
  int k = idx - n * K;
  WT[idx] = f2bf(W[(size_t)k * Nn + n]);
}

// ---------------- mean aggregation (CSR gather) ----------------
// one block per node; bf16 in, fp32 accumulate, bf16 out. F % 4 == 0.
template <int CH>
__global__ __launch_bounds__(256)
void gs_agg_mean(const unsigned short* __restrict__ X, const int* __restrict__ rp,
                 const int* __restrict__ col, unsigned short* __restrict__ out, int F) {
  const int v = blockIdx.x;
  const int tid = threadIdx.x;
  const int s0 = rp[v], s1 = rp[v + 1];
  const float inv = 1.0f / (float)max(s1 - s0, 1);
  const int G = F >> 2;

  f32x4 acc[CH];
#pragma unroll
  for (int c = 0; c < CH; ++c) acc[c] = (f32x4){0.f, 0.f, 0.f, 0.f};

  __shared__ int nb[256];
  for (int base = s0; base < s1; base += 256) {
    int m = min(s1 - base, 256);
    __syncthreads();
    if (tid < m) nb[tid] = col[base + tid];
    __syncthreads();
    for (int j = 0; j < m; ++j) {
      const unsigned short* xr = X + (size_t)nb[j] * F;
#pragma unroll
      for (int c = 0; c < CH; ++c) {
        int g = tid + c * 256;
        if (g < G) {
          ushort4 u = *(const ushort4*)(xr + g * 4);
          acc[c][0] += bf2f(u.x);
          acc[c][1] += bf2f(u.y);
          acc[c][2] += bf2f(u.z);
          acc[c][3] += bf2f(u.w);
        }
      }
    }
  }
  unsigned short* orow = out + (size_t)v * F;
#pragma unroll
  for (int c = 0; c < CH; ++c) {
    int g = tid + c * 256;
    if (g < G) {
      ushort4 o;
      o.x = f2bf(acc[c][0] * inv);
      o.y = f2bf(acc[c][1] * inv);
      o.z = f2bf(acc[c][2] * inv);
      o.w = f2bf(acc[c][3] * inv);
      *(ushort4*)(orow + g * 4) = o;
    }
  }
}

// ---------------- fused dual-GEMM:  C = act(A1@B1^T + A2@B2^T + bias) ----------------
// A row-major M x K (bf16), B given TRANSPOSED: Nn x K row-major (bf16).
// 128x128 block tile, BK=32, 4 waves of 4x4 16x16x32 MFMA. Nn % 128 == 0, K % 32 == 0.
__global__ __launch_bounds__(256)
void gs_gemm2(const unsigned short* __restrict__ A1, const unsigned short* __restrict__ A2,
              const unsigned short* __restrict__ B1, const unsigned short* __restrict__ B2,
              const float* __restrict__ bias,
              unsigned short* __restrict__ Hout, float* __restrict__ Fout,
              int M, int Nn, int K, int doRelu) {
  __shared__ unsigned short lA[128 * 32];
  __shared__ unsigned short lB[128 * 32];
  const int tid = threadIdx.x;
  const int wid = tid >> 6;
  const int lane = tid & 63;
  const int bM = blockIdx.x * 128;
  const int bN = blockIdx.y * 128;
  const int wM = (wid >> 1) * 64;
  const int wN = (wid & 1) * 64;

  f32x4 acc[4][4];
#pragma unroll
  for (int i = 0; i < 4; ++i)
#pragma unroll
    for (int j = 0; j < 4; ++j) acc[i][j] = (f32x4){0.f, 0.f, 0.f, 0.f};

  const int mrow = wM + (lane & 15);
  const int nrow = wN + (lane & 15);
  const int kof = (lane >> 4) * 8;

  for (int pass = 0; pass < 2; ++pass) {
    const unsigned short* Ap = pass ? A2 : A1;
    const unsigned short* Bp = pass ? B2 : B1;
    for (int k0 = 0; k0 < K; k0 += 32) {
#pragma unroll
      for (int r = 0; r < 2; ++r) {
        int row = r * 64 + (tid >> 2);
        int ga = bM + row;
        if (ga >= M) ga = M - 1;                      // clamp: OOB rows never stored
        const unsigned short* gpA = Ap + (size_t)ga * K + k0 + (tid & 3) * 8;
        const unsigned short* gpB = Bp + (size_t)(bN + row) * K + k0 + (tid & 3) * 8;
        unsigned lo = r * 4096 + wid * 1024;          // wave-uniform LDS base (+lane*16 by HW)
        __builtin_amdgcn_global_load_lds(
            (const __attribute__((address_space(1))) unsigned int*)gpA,
            (__attribute__((address_space(3))) unsigned int*)((char*)lA + lo), 16, 0, 0);
        __builtin_amdgcn_global_load_lds(
            (const __attribute__((address_space(1))) unsigned int*)gpB,
            (__attribute__((address_space(3))) unsigned int*)((char*)lB + lo), 16, 0, 0);
      }
      __syncthreads();
      short8 aF[4], bF[4];
#pragma unroll
      for (int i = 0; i < 4; ++i) {
        aF[i] = *(const short8*)&lA[(mrow + i * 16) * 32 + kof];
        bF[i] = *(const short8*)&lB[(nrow + i * 16) * 32 + kof];
      }
#pragma unroll
      for (int i = 0; i < 4; ++i)
#pragma unroll
        for (int j = 0; j < 4; ++j)
          acc[i][j] = __builtin_amdgcn_mfma_f32_16x16x32_bf16(aF[i], bF[j], acc[i][j], 0, 0, 0);
      __syncthreads();
    }
  }

  // C/D layout: col = lane&15, row = (lane>>4)*4 + reg   [measured m89/m91]
  const int rbase = bM + wM + (lane >> 4) * 4;
#pragma unroll
  for (int i = 0; i < 4; ++i) {
#pragma unroll
    for (int r = 0; r < 4; ++r) {
      int row = rbase + i * 16 + r;
      if (row >= M) continue;
#pragma unroll
      for (int j = 0; j < 4; ++j) {
        int colN = bN + wN + j * 16 + (lane & 15);
        float v = acc[i][j][r] + bias[colN];
        if (doRelu) v = fmaxf(v, 0.f);
        Hout[(size_t)row * Nn + colN] = f2bf(v);
        if (Fout) Fout[(size_t)row * Nn + colN] = v;
      }
    }
  }
}

// ---------------- layer 5: [N,256]x2 -> [N,5], fp32, one wave per node ----------------
__global__ __launch_bounds__(64)
void gs_layer5(const unsigned short* __restrict__ agg, const unsigned short* __restrict__ h,
               const float* __restrict__ Wl, const float* __restrict__ Wr,
               const float* __restrict__ b, float* __restrict__ out) {
  __shared__ float sW[2560];
  const int v = blockIdx.x;
  const int l = threadIdx.x;
  for (int i = l; i < 2560; i += 64) sW[i] = (i < 1280) ? Wl[i] : Wr[i - 1280];
  __syncthreads();
  float acc[5] = {0.f, 0.f, 0.f, 0.f, 0.f};
  const unsigned short* ar = agg + (size_t)v * 256;
  const unsigned short* hr = h + (size_t)v * 256;
  for (int k = l; k < 256; k += 64) {
    float a = bf2f(ar[k]);
    float hh = bf2f(hr[k]);
#pragma unroll
    for (int n = 0; n < 5; ++n) acc[n] += a * sW[k * 5 + n] + hh * sW[1280 + k * 5 + n];
  }
#pragma unroll
  for (int n = 0; n < 5; ++n)
    for (int off = 32; off > 0; off >>= 1) acc[n] += __shfl_down(acc[n], off, 64);
  if (l == 0) {
#pragma unroll
    for (int n = 0; n < 5; ++n) out[(size_t)v * 5 + n] = acc[n] + b[n];
  }
}

// ---------------- launcher ----------------
extern "C" void kernel_launch(void* const* d_in, const int* in_sizes, int n_in,
                              void* d_out, int out_size, void* d_ws, size_t ws_size,
                              hipStream_t stream) {
  const float* x = (const float*)d_in[0];
  const int* ei = (const int*)d_in[1];
  const int N = in_sizes[0] / 768;
  const int E = in_sizes[1] / 2;
  const int* src = ei;
  const int* dst = ei + E;

  const int FI[5] = {768, 1536, 768, 384, 256};
  const int FO[5] = {1536, 768, 384, 256, 5};
  const float* Wl[5];
  const float* Wr[5];
  const float* bb[5];
  for (int l = 0; l < 5; ++l) {
    Wl[l] = (const float*)d_in[2 + 3 * l];
    Wr[l] = (const float*)d_in[3 + 3 * l];
    bb[l] = (const float*)d_in[4 + 3 * l];
  }

  char* w = (char*)d_ws;
  size_t off = 0;
  auto take = [&](size_t bytes) -> char* {
    char* p = w + off;
    off = (off + bytes + 255) & ~(size_t)255;
    return p;
  };
  unsigned short* xb   = (unsigned short*)take((size_t)N * 768 * 2);   // also reused as h2
  unsigned short* h1   = (unsigned short*)take((size_t)N * 1536 * 2);
  unsigned short* aggb = (unsigned short*)take((size_t)N * 1536 * 2);
  unsigned short* h3   = (unsigned short*)take((size_t)N * 384 * 2);
  unsigned short* h4b  = (unsigned short*)take((size_t)N * 256 * 2);
  int* cnt = (int*)take((size_t)N * 4);
  int* rp  = (int*)take((size_t)(N + 1) * 4);
  int* cur = (int*)take((size_t)N * 4);
  int* col = (int*)take((size_t)E * 4);
  unsigned short* WT[8];
  for (int l = 0; l < 4; ++l) {
    WT[2 * l]     = (unsigned short*)take((size_t)FI[l] * FO[l] * 2);
    WT[2 * l + 1] = (unsigned short*)take((size_t)FI[l] * FO[l] * 2);
  }
  unsigned short* h2 = xb;
  const int M = N;
  const int Mt = (M + 127) / 128;

  // CSR build
  gs_zero_i32<<<(N + 255) / 256, 256, 0, stream>>>(cnt, N);
  gs_count_deg<<<(E + 255) / 256, 256, 0, stream>>>(dst, cnt, E);
  gs_scan_csr<<<1, 1024, 0, stream>>>(cnt, rp, cur, N);
  gs_fill_csr<<<(E + 255) / 256, 256, 0, stream>>>(src, dst, cur, col, E);

  // input + weight conversion
  gs_f32_to_bf16<<<((N * 768 / 4) + 255) / 256, 256, 0, stream>>>(x, xb, N * 768 / 4);
  for (int l = 0; l < 4; ++l) {
    int tot = FI[l] * FO[l];
    gs_pack_wt<<<(tot + 255) / 256, 256, 0, stream>>>(Wl[l], WT[2 * l], FI[l], FO[l]);
    gs_pack_wt<<<(tot + 255) / 256, 256, 0, stream>>>(Wr[l], WT[2 * l + 1], FI[l], FO[l]);
  }

  float* houtF = (float*)d_out;                 // [N,256] fp32
  float* out5  = (float*)d_out + (size_t)N * 256;

  // L1: 768 -> 1536
  gs_agg_mean<1><<<N, 256, 0, stream>>>(xb, rp, col, aggb, 768);
  gs_gemm2<<<dim3(Mt, 12), 256, 0, stream>>>(aggb, xb, WT[0], WT[1], bb[0], h1, nullptr, M, 1536, 768, 1);
  // L2: 1536 -> 768
  gs_agg_mean<2><<<N, 256, 0, stream>>>(h1, rp, col, aggb, 1536);
  gs_gemm2<<<dim3(Mt, 6), 256, 0, stream>>>(aggb, h1, WT[2], WT[3], bb[1], h2, nullptr, M, 768, 1536, 1);
  // L3: 768 -> 384
  gs_agg_mean<1><<<N, 256, 0, stream>>>(h2, rp, col, aggb, 768);
  gs_gemm2<<<dim3(Mt, 3), 256, 0, stream>>>(aggb, h2, WT[4], WT[5], bb[2], h3, nullptr, M, 384, 768, 1);
  // L4: 384 -> 256  (dual store: bf16 for L5 + fp32 to d_out)
  gs_agg_mean<1><<<N, 256, 0, stream>>>(h3, rp, col, aggb, 384);
  gs_gemm2<<<dim3(Mt, 2), 256, 0, stream>>>(aggb, h3, WT[6], WT[7], bb[3], h4b, houtF, M, 256, 384, 1);
  // L5: 256 -> 5
  gs_agg_mean<1><<<N, 256, 0, stream>>>(h4b, rp, col, aggb, 256);
  gs_layer5<<<N, 64, 0, stream>>>(aggb, h4b, Wl[4], Wr[4], bb[4], out5);
}

// Round 2
// 802.790 us; speedup vs baseline: 1.3922x; 1.3922x over previous
//
#include <hip/hip_runtime.h>
#include <stdint.h>

typedef __attribute__((ext_vector_type(8))) short short8;
typedef __attribute__((ext_vector_type(4))) float f32x4;

__device__ __forceinline__ float bf2f(unsigned short s) {
  return __uint_as_float(((unsigned)s) << 16);
}
__device__ __forceinline__ unsigned short f2bf(float f) {
  unsigned u = __float_as_uint(f);
  u += 0x7fffu + ((u >> 16) & 1u);   // round-to-nearest-even
  return (unsigned short)(u >> 16);
}

// ---------------- CSR build ----------------
__global__ void gs_zero_i32(int* p, int n) {
  int i = blockIdx.x * 256 + threadIdx.x;
  if (i < n) p[i] = 0;
}

__global__ void gs_count_deg(const int* __restrict__ dst, int* __restrict__ cnt, int E) {
  int e = blockIdx.x * 256 + threadIdx.x;
  if (e < E) atomicAdd(&cnt[dst[e]], 1);
}

// 3-phase scan: A) per-1024-chunk local exclusive scan + chunk sum
__global__ void gs_scanA(const int* __restrict__ cnt, int* __restrict__ rp,
                         int* __restrict__ bsum, int n) {
  __shared__ int sm[256];
  const int b = blockIdx.x, t = threadIdx.x;
  const int base = b * 1024 + t * 4;
  int v[4]; int s = 0;
#pragma unroll
  for (int i = 0; i < 4; ++i) { v[i] = (base + i < n) ? cnt[base + i] : 0; s += v[i]; }
  sm[t] = s;
  __syncthreads();
  for (int off = 1; off < 256; off <<= 1) {
    int x = (t >= off) ? sm[t - off] : 0;
    __syncthreads();
    sm[t] += x;
    __syncthreads();
  }
  int run = sm[t] - s;
#pragma unroll
  for (int i = 0; i < 4; ++i) { if (base + i < n) rp[base + i] = run; run += v[i]; }
  if (t == 255) bsum[b] = sm[255];
}

// B) serial scan of chunk sums (tiny: ~20 entries), total stored at bsum[nb]
__global__ void gs_scanB(int* bsum, int nb) {
  if (threadIdx.x == 0 && blockIdx.x == 0) {
    int run = 0;
    for (int i = 0; i < nb; ++i) { int v = bsum[i]; bsum[i] = run; run += v; }
    bsum[nb] = run;
  }
}

// C) add chunk offsets, replicate into cur, set rp[n]
__global__ void gs_scanC(int* __restrict__ rp, int* __restrict__ cur,
                         const int* __restrict__ bsum, int n, int nb) {
  int i = blockIdx.x * 256 + threadIdx.x;
  if (i < n) {
    int v = rp[i] + bsum[i >> 10];
    rp[i] = v;
    cur[i] = v;
  }
  if (i == n) rp[n] = bsum[nb];
}

__global__ void gs_fill_csr(const int* __restrict__ src, const int* __restrict__ dst,
                            int* __restrict__ cur, int* __restrict__ col, int E) {
  int e = blockIdx.x * 256 + threadIdx.x;
  if (e < E) {
    int pos = atomicAdd(&cur[dst[e]], 1);
    col[pos] = src[e];
  }
}

// ---------------- conversions / weight packing ----------------
__global__ void gs_f32_to_bf16(const float* __restrict__ in, unsigned short* __restrict__ out, int n4) {
  int i = blockIdx.x * 256 + threadIdx.x;
  if (i < n4) {
    float4 f = ((const float4*)in)[i];
    ushort4 o;
    o.x = f2bf(f.x); o.y = f2bf(f.y); o.z = f2bf(f.z); o.w = f2bf(f.w);
    ((ushort4*)out)[i] = o;
  }
}

// W [K x Nn] fp32 row-major -> WT [Nn x K] bf16 row-major (B^T layout)
__global__ void gs_pack_wt(const float* __restrict__ W, unsigned short* __restrict__ WT,
                           int K, int Nn) {
  int idx = blockIdx.x * 256 + threadIdx.x;
  if (idx >= K * Nn) return;
  int n = idx / K;
  int k = idx - n * K;
  WT[idx] = f2bf(W[(size_t)k * Nn + n]);
}

// concat pack: WT [(2F) x K]; rows [0,F)=Wl^T, rows [F,2F)=Wr^T  (Wl,Wr are [K x F])
__global__ void gs_pack_wt2(const float* __restrict__ Wl, const float* __restrict__ Wr,
                            unsigned short* __restrict__ WT, int K, int F) {
  int idx = blockIdx.x * 256 + threadIdx.x;
  if (idx >= 2 * F * K) return;
  int row = idx / K;
  int k = idx - row * K;
  float v = (row < F) ? Wl[(size_t)k * F + row] : Wr[(size_t)k * F + (row - F)];
  WT[idx] = f2bf(v);
}

// ---------------- fused post-aggregation ----------------
// h[v] = act( mean_{nb} y[nb] + z[v] + bias ), y = C[:, 0:F), z = C[:, zoff:zoff+F)
// zoff<0 -> plain mean (L1 pre-agg). TPB*W == F.
template <int F, int TPB, int W>
__global__ __launch_bounds__(TPB)
void gs_agg_post(const unsigned short* __restrict__ C, int ldc, int zoff,
                 const int* __restrict__ rp, const int* __restrict__ col,
                 const float* __restrict__ bias,
                 unsigned short* __restrict__ hout, float* __restrict__ fout, int relu) {
  static_assert(TPB * W == F, "layout");
  const int v = blockIdx.x;
  const int tid = threadIdx.x;
  const int s0 = rp[v], s1 = rp[v + 1];
  const float inv = 1.0f / (float)max(s1 - s0, 1);
  float acc[W];
#pragma unroll
  for (int w = 0; w < W; ++w) acc[w] = 0.f;

  __shared__ int nb[TPB];
  for (int base = s0; base < s1; base += TPB) {
    int m = min(s1 - base, TPB);
    __syncthreads();
    if (tid < m) nb[tid] = col[base + tid];
    __syncthreads();
    for (int j = 0; j < m; ++j) {
      const unsigned short* xr = C + (size_t)nb[j] * ldc + tid * W;
      if constexpr (W == 4) {
        ushort4 u = *(const ushort4*)xr;
        acc[0] += bf2f(u.x); acc[1] += bf2f(u.y); acc[2] += bf2f(u.z); acc[3] += bf2f(u.w);
      } else {
        ushort2 u = *(const ushort2*)xr;
        acc[0] += bf2f(u.x); acc[1] += bf2f(u.y);
      }
    }
  }

  float o[W];
#pragma unroll
  for (int w = 0; w < W; ++w) o[w] = acc[w] * inv;
  if (zoff >= 0) {
    const unsigned short* zr = C + (size_t)v * ldc + zoff + tid * W;
    if constexpr (W == 4) {
      ushort4 u = *(const ushort4*)zr;
      o[0] += bf2f(u.x); o[1] += bf2f(u.y); o[2] += bf2f(u.z); o[3] += bf2f(u.w);
    } else {
      ushort2 u = *(const ushort2*)zr;
      o[0] += bf2f(u.x); o[1] += bf2f(u.y);
    }
  }
  if (bias) {
#pragma unroll
    for (int w = 0; w < W; ++w) o[w] += bias[tid * W + w];
  }
  if (relu) {
#pragma unroll
    for (int w = 0; w < W; ++w) o[w] = fmaxf(o[w], 0.f);
  }
  if (hout) {
    if constexpr (W == 4) {
      ushort4 u; u.x = f2bf(o[0]); u.y = f2bf(o[1]); u.z = f2bf(o[2]); u.w = f2bf(o[3]);
      *(ushort4*)(hout + (size_t)v * F + tid * W) = u;
    } else {
      ushort2 u; u.x = f2bf(o[0]); u.y = f2bf(o[1]);
      *(ushort2*)(hout + (size_t)v * F + tid * W) = u;
    }
  }
  if (fout) {
    if constexpr (W == 4) {
      *(float4*)(fout + (size_t)v * F + tid * W) = make_float4(o[0], o[1], o[2], o[3]);
    } else {
      *(float2*)(fout + (size_t)v * F + tid * W) = make_float2(o[0], o[1]);
    }
  }
}

// ---------------- GEMM: C = act(A1@B1^T [+ A2@B2^T] + bias) ----------------
// A row-major M x K (bf16), B TRANSPOSED: Nn x K row-major (bf16).
// 128x128 tile, BK=32, 4 waves of 4x4 16x16x32 MFMA. Nn%128==0, K%32==0.
// 1-D grid, swizzled: groups of MG M-tiles sweep all N-tiles (A stays L2-hot).
__global__ __launch_bounds__(256)
void gs_gemm(const unsigned short* __restrict__ A1, const unsigned short* __restrict__ A2,
             const unsigned short* __restrict__ B1, const unsigned short* __restrict__ B2,
             const float* __restrict__ bias, unsigned short* __restrict__ Hout,
             int M, int Nn, int K, int doRelu, int Mt, int Nt) {
  __shared__ unsigned short lA[128 * 32];
  __shared__ unsigned short lB[128 * 32];
  const int tid = threadIdx.x;
  const int wid = tid >> 6;
  const int lane = tid & 63;

  // swizzle: group of MG M-tiles x all N-tiles
  const int MG = 8;
  const int per = MG * Nt;
  const int g = blockIdx.x / per;
  const int rem = blockIdx.x - g * per;
  const int gsz = min(MG, Mt - g * MG);
  const int nIdx = rem / gsz;
  const int mIdx = g * MG + (rem - nIdx * gsz);
  const int bM = mIdx * 128;
  const int bN = nIdx * 128;
  const int wM = (wid >> 1) * 64;
  const int wN = (wid & 1) * 64;

  f32x4 acc[4][4];
#pragma unroll
  for (int i = 0; i < 4; ++i)
#pragma unroll
    for (int j = 0; j < 4; ++j) acc[i][j] = (f32x4){0.f, 0.f, 0.f, 0.f};

  const int mrow = wM + (lane & 15);
  const int nrow = wN + (lane & 15);
  const int kof = (lane >> 4) * 8;
  const int npass = A2 ? 2 : 1;

  for (int pass = 0; pass < npass; ++pass) {
    const unsigned short* Ap = pass ? A2 : A1;
    const unsigned short* Bp = pass ? B2 : B1;
    for (int k0 = 0; k0 < K; k0 += 32) {
#pragma unroll
      for (int r = 0; r < 2; ++r) {
        int row = r * 64 + (tid >> 2);
        int ga = bM + row;
        if (ga >= M) ga = M - 1;                      // clamp: OOB rows never stored
        const unsigned short* gpA = Ap + (size_t)ga * K + k0 + (tid & 3) * 8;
        const unsigned short* gpB = Bp + (size_t)(bN + row) * K + k0 + (tid & 3) * 8;
        unsigned lo = r * 4096 + wid * 1024;          // wave-uniform LDS base (+lane*16 by HW)
        __builtin_amdgcn_global_load_lds(
            (const __attribute__((address_space(1))) unsigned int*)gpA,
            (__attribute__((address_space(3))) unsigned int*)((char*)lA + lo), 16, 0, 0);
        __builtin_amdgcn_global_load_lds(
            (const __attribute__((address_space(1))) unsigned int*)gpB,
            (__attribute__((address_space(3))) unsigned int*)((char*)lB + lo), 16, 0, 0);
      }
      __syncthreads();
      short8 aF[4], bF[4];
#pragma unroll
      for (int i = 0; i < 4; ++i) {
        aF[i] = *(const short8*)&lA[(mrow + i * 16) * 32 + kof];
        bF[i] = *(const short8*)&lB[(nrow + i * 16) * 32 + kof];
      }
#pragma unroll
      for (int i = 0; i < 4; ++i)
#pragma unroll
        for (int j = 0; j < 4; ++j)
          acc[i][j] = __builtin_amdgcn_mfma_f32_16x16x32_bf16(aF[i], bF[j], acc[i][j], 0, 0, 0);
      __syncthreads();
    }
  }

  // C/D layout: col = lane&15, row = (lane>>4)*4 + reg   [m89/m91]
  const int rbase = bM + wM + (lane >> 4) * 4;
#pragma unroll
  for (int i = 0; i < 4; ++i) {
#pragma unroll
    for (int r = 0; r < 4; ++r) {
      int row = rbase + i * 16 + r;
      if (row >= M) continue;
#pragma unroll
      for (int j = 0; j < 4; ++j) {
        int colN = bN + wN + j * 16 + (lane & 15);
        float v = acc[i][j][r];
        if (bias) v += bias[colN];
        if (doRelu) v = fmaxf(v, 0.f);
        Hout[(size_t)row * Nn + colN] = f2bf(v);
      }
    }
  }
}

// ---------------- layer 5 ----------------
// yz[v, 0:5] = h4[v]@Wl5, yz[v, 5:10] = h4[v]@Wr5   (fp32)
__global__ __launch_bounds__(64)
void gs_l5dot(const unsigned short* __restrict__ h4, const float* __restrict__ Wl,
              const float* __restrict__ Wr, float* __restrict__ yz) {
  __shared__ float sW[2560];
  const int v = blockIdx.x;
  const int l = threadIdx.x;
  for (int i = l; i < 2560; i += 64) sW[i] = (i < 1280) ? Wl[i] : Wr[i - 1280];
  __syncthreads();
  ushort4 u = ((const ushort4*)(h4 + (size_t)v * 256))[l];   // k = 4l..4l+3
  float hv[4] = {bf2f(u.x), bf2f(u.y), bf2f(u.z), bf2f(u.w)};
  float acc[10];
#pragma unroll
  for (int n = 0; n < 10; ++n) acc[n] = 0.f;
#pragma unroll
  for (int t = 0; t < 4; ++t) {
    int k = 4 * l + t;
#pragma unroll
    for (int n = 0; n < 5; ++n) {
      acc[n] += hv[t] * sW[k * 5 + n];
      acc[5 + n] += hv[t] * sW[1280 + k * 5 + n];
    }
  }
#pragma unroll
  for (int n = 0; n < 10; ++n)
    for (int off = 32; off > 0; off >>= 1) acc[n] += __shfl_down(acc[n], off, 64);
  if (l == 0) {
#pragma unroll
    for (int n = 0; n < 10; ++n) yz[(size_t)v * 10 + n] = acc[n];
  }
}

// out[v] = mean_{nb} y5[nb] + z5[v] + b  (no relu)
__global__ __launch_bounds__(64)
void gs_l5agg(const float* __restrict__ yz, const int* __restrict__ rp,
              const int* __restrict__ col, const float* __restrict__ b,
              float* __restrict__ out) {
  const int v = blockIdx.x;
  const int l = threadIdx.x;
  const int s0 = rp[v], s1 = rp[v + 1];
  const float inv = 1.0f / (float)max(s1 - s0, 1);
  float acc[5] = {0.f, 0.f, 0.f, 0.f, 0.f};
  for (int e = s0 + l; e < s1; e += 64) {
    const float* yr = yz + (size_t)col[e] * 10;
#pragma unroll
    for (int n = 0; n < 5; ++n) acc[n] += yr[n];
  }
#pragma unroll
  for (int n = 0; n < 5; ++n)
    for (int off = 32; off > 0; off >>= 1) acc[n] += __shfl_down(acc[n], off, 64);
  if (l == 0) {
#pragma unroll
    for (int n = 0; n < 5; ++n)
      out[(size_t)v * 5 + n] = acc[n] * inv + yz[(size_t)v * 10 + 5 + n] + b[n];
  }
}

// ---------------- launcher ----------------
extern "C" void kernel_launch(void* const* d_in, const int* in_sizes, int n_in,
                              void* d_out, int out_size, void* d_ws, size_t ws_size,
                              hipStream_t stream) {
  const float* x = (const float*)d_in[0];
  const int* ei = (const int*)d_in[1];
  const int N = in_sizes[0] / 768;
  const int E = in_sizes[1] / 2;
  const int* src = ei;
  const int* dst = ei + E;

  const float* Wl[5];
  const float* Wr[5];
  const float* bb[5];
  for (int l = 0; l < 5; ++l) {
    Wl[l] = (const float*)d_in[2 + 3 * l];
    Wr[l] = (const float*)d_in[3 + 3 * l];
    bb[l] = (const float*)d_in[4 + 3 * l];
  }

  char* w = (char*)d_ws;
  size_t off = 0;
  auto take = [&](size_t bytes) -> char* {
    char* p = w + off;
    off = (off + bytes + 255) & ~(size_t)255;
    return p;
  };
  // arenas (aliased over layer lifetime)
  unsigned short* ar1 = (unsigned short*)take((size_t)N * 768 * 2);   // xb -> C3
  unsigned short* ar2 = (unsigned short*)take((size_t)N * 768 * 2);   // aggb -> h2
  unsigned short* ar3 = (unsigned short*)take((size_t)N * 1536 * 2);  // h1 -> C4|h3|h4|yz5
  unsigned short* C2  = (unsigned short*)take((size_t)N * 1536 * 2);
  int* cnt  = (int*)take((size_t)N * 4);
  int* rp   = (int*)take((size_t)(N + 1) * 4);
  int* cur  = (int*)take((size_t)N * 4);
  int* col  = (int*)take((size_t)E * 4);
  const int nbChunks = (N + 1023) / 1024;
  int* bsum = (int*)take((size_t)(nbChunks + 1) * 4);
  unsigned short* WT1l = (unsigned short*)take((size_t)1536 * 768 * 2);
  unsigned short* WT1r = (unsigned short*)take((size_t)1536 * 768 * 2);
  unsigned short* WT2  = (unsigned short*)take((size_t)1536 * 1536 * 2);
  unsigned short* WT3  = (unsigned short*)take((size_t)768 * 768 * 2);
  unsigned short* WT4  = (unsigned short*)take((size_t)512 * 384 * 2);

  unsigned short* xb   = ar1;
  unsigned short* C3   = ar1;
  unsigned short* aggb = ar2;
  unsigned short* h2   = ar2;
  unsigned short* h1   = ar3;
  unsigned short* C4   = ar3;                                  // N x 512
  unsigned short* h3   = ar3 + (size_t)N * 512;                // N x 384
  unsigned short* h4   = ar3 + (size_t)N * (512 + 384);        // N x 256
  float*          yz5  = (float*)(ar3 + (size_t)N * (512 + 384 + 256)); // N x 10 f32

  const int M = N;
  const int Mt = (M + 127) / 128;

  // CSR build
  gs_zero_i32<<<(N + 255) / 256, 256, 0, stream>>>(cnt, N);
  gs_count_deg<<<(E + 255) / 256, 256, 0, stream>>>(dst, cnt, E);
  gs_scanA<<<nbChunks, 256, 0, stream>>>(cnt, rp, bsum, N);
  gs_scanB<<<1, 64, 0, stream>>>(bsum, nbChunks);
  gs_scanC<<<(N + 256) / 256, 256, 0, stream>>>(rp, cur, bsum, N, nbChunks);
  gs_fill_csr<<<(E + 255) / 256, 256, 0, stream>>>(src, dst, cur, col, E);

  // conversions
  gs_f32_to_bf16<<<((N * 768 / 4) + 255) / 256, 256, 0, stream>>>(x, xb, N * 768 / 4);
  gs_pack_wt<<<(1536 * 768 + 255) / 256, 256, 0, stream>>>(Wl[0], WT1l, 768, 1536);
  gs_pack_wt<<<(1536 * 768 + 255) / 256, 256, 0, stream>>>(Wr[0], WT1r, 768, 1536);
  gs_pack_wt2<<<(2 * 768 * 1536 + 255) / 256, 256, 0, stream>>>(Wl[1], Wr[1], WT2, 1536, 768);
  gs_pack_wt2<<<(2 * 384 * 768 + 255) / 256, 256, 0, stream>>>(Wl[2], Wr[2], WT3, 768, 384);
  gs_pack_wt2<<<(2 * 256 * 384 + 255) / 256, 256, 0, stream>>>(Wl[3], Wr[3], WT4, 384, 256);

  float* houtF = (float*)d_out;                 // [N,256] fp32
  float* out5  = (float*)d_out + (size_t)N * 256;

  // L1: agg-before (Fin 768 < Fout 1536), dual GEMM -> h1 (relu+bias)
  gs_agg_post<768, 192, 4><<<N, 192, 0, stream>>>(xb, 768, -1, rp, col, nullptr, aggb, nullptr, 0);
  gs_gemm<<<Mt * 12, 256, 0, stream>>>(aggb, xb, WT1l, WT1r, bb[0], h1, M, 1536, 768, 1, Mt, 12);

  // L2: GEMM C2 = h1 @ [Wl2|Wr2]  (N x 1536), fused agg over 768 -> h2
  gs_gemm<<<Mt * 12, 256, 0, stream>>>(h1, nullptr, WT2, nullptr, nullptr, C2, M, 1536, 1536, 0, Mt, 12);
  gs_agg_post<768, 192, 4><<<N, 192, 0, stream>>>(C2, 1536, 768, rp, col, bb[1], h2, nullptr, 1);

  // L3: GEMM C3 = h2 @ [Wl3|Wr3]  (N x 768), fused agg over 384 -> h3
  gs_gemm<<<Mt * 6, 256, 0, stream>>>(h2, nullptr, WT3, nullptr, nullptr, C3, M, 768, 768, 0, Mt, 6);
  gs_agg_post<384, 192, 2><<<N, 192, 0, stream>>>(C3, 768, 384, rp, col, bb[2], h3, nullptr, 1);

  // L4: GEMM C4 = h3 @ [Wl4|Wr4]  (N x 512), fused agg over 256 -> h4 (bf16) + d_out (fp32)
  gs_gemm<<<Mt * 4, 256, 0, stream>>>(h3, nullptr, WT4, nullptr, nullptr, C4, M, 512, 384, 0, Mt, 4);
  gs_agg_post<256, 64, 4><<<N, 64, 0, stream>>>(C4, 512, 256, rp, col, bb[3], h4, houtF, 1);

  // L5: per-node dot -> yz5 [N,10] fp32, then tiny agg over 5 -> out
  gs_l5dot<<<N, 64, 0, stream>>>(h4, Wl[4], Wr[4], yz5);
  gs_l5agg<<<N, 64, 0, stream>>>(yz5, rp, col, bb[4], out5);
}

// Round 3
// 727.088 us; speedup vs baseline: 1.5371x; 1.1041x over previous
//
#include <hip/hip_runtime.h>
#include <stdint.h>

typedef __attribute__((ext_vector_type(8))) short short8;
typedef __attribute__((ext_vector_type(4))) float f32x4;

__device__ __forceinline__ float bf2f(unsigned short s) {
  return __uint_as_float(((unsigned)s) << 16);
}
__device__ __forceinline__ unsigned short f2bf(float f) {
  unsigned u = __float_as_uint(f);
  u += 0x7fffu + ((u >> 16) & 1u);   // round-to-nearest-even
  return (unsigned short)(u >> 16);
}

// ---------------- CSR build ----------------
__global__ void gs_zero_i32(int* p, int n) {
  int i = blockIdx.x * 256 + threadIdx.x;
  if (i < n) p[i] = 0;
}

__global__ void gs_count_deg(const int* __restrict__ dst, int* __restrict__ cnt, int E) {
  int e = blockIdx.x * 256 + threadIdx.x;
  if (e < E) atomicAdd(&cnt[dst[e]], 1);
}

// 3-phase scan: A) per-1024-chunk local exclusive scan + chunk sum
__global__ void gs_scanA(const int* __restrict__ cnt, int* __restrict__ rp,
                         int* __restrict__ bsum, int n) {
  __shared__ int sm[256];
  const int b = blockIdx.x, t = threadIdx.x;
  const int base = b * 1024 + t * 4;
  int v[4]; int s = 0;
#pragma unroll
  for (int i = 0; i < 4; ++i) { v[i] = (base + i < n) ? cnt[base + i] : 0; s += v[i]; }
  sm[t] = s;
  __syncthreads();
  for (int off = 1; off < 256; off <<= 1) {
    int x = (t >= off) ? sm[t - off] : 0;
    __syncthreads();
    sm[t] += x;
    __syncthreads();
  }
  int run = sm[t] - s;
#pragma unroll
  for (int i = 0; i < 4; ++i) { if (base + i < n) rp[base + i] = run; run += v[i]; }
  if (t == 255) bsum[b] = sm[255];
}

// B) serial scan of chunk sums (~20 entries), total stored at bsum[nb]
__global__ void gs_scanB(int* bsum, int nb) {
  if (threadIdx.x == 0 && blockIdx.x == 0) {
    int run = 0;
    for (int i = 0; i < nb; ++i) { int v = bsum[i]; bsum[i] = run; run += v; }
    bsum[nb] = run;
  }
}

// C) add chunk offsets, replicate into cur, set rp[n]
__global__ void gs_scanC(int* __restrict__ rp, int* __restrict__ cur,
                         const int* __restrict__ bsum, int n, int nb) {
  int i = blockIdx.x * 256 + threadIdx.x;
  if (i < n) {
    int v = rp[i] + bsum[i >> 10];
    rp[i] = v;
    cur[i] = v;
  }
  if (i == n) rp[n] = bsum[nb];
}

__global__ void gs_fill_csr(const int* __restrict__ src, const int* __restrict__ dst,
                            int* __restrict__ cur, int* __restrict__ col, int E) {
  int e = blockIdx.x * 256 + threadIdx.x;
  if (e < E) {
    int pos = atomicAdd(&cur[dst[e]], 1);
    col[pos] = src[e];
  }
}

// ---------------- conversions / weight packing ----------------
__global__ void gs_f32_to_bf16(const float* __restrict__ in, unsigned short* __restrict__ out, int n4) {
  int i = blockIdx.x * 256 + threadIdx.x;
  if (i < n4) {
    float4 f = ((const float4*)in)[i];
    ushort4 o;
    o.x = f2bf(f.x); o.y = f2bf(f.y); o.z = f2bf(f.z); o.w = f2bf(f.w);
    ((ushort4*)out)[i] = o;
  }
}

// tiled transpose-pack: W [K x F] fp32 row-major -> WT [F x K] bf16 row-major.
// coalesced reads (along F) and writes (along K).
__global__ void gs_tpack(const float* __restrict__ W, unsigned short* __restrict__ WT,
                         int K, int F) {
  __shared__ float t[32][33];
  const int k0 = blockIdx.x * 32, f0 = blockIdx.y * 32;
  const int tx = threadIdx.x, ty = threadIdx.y;
#pragma unroll
  for (int r = ty; r < 32; r += 8) {
    int k = k0 + r, f = f0 + tx;
    t[r][tx] = (k < K && f < F) ? W[(size_t)k * F + f] : 0.f;
  }
  __syncthreads();
#pragma unroll
  for (int r = ty; r < 32; r += 8) {
    int f = f0 + r, k = k0 + tx;
    if (f < F && k < K) WT[(size_t)f * K + k] = f2bf(t[tx][r]);
  }
}

// ---------------- fused post-aggregation ----------------
// h[v] = act( mean_{nb} y[nb] + z[v] + bias ), y = C[:, 0:F), z = C[:, zoff:zoff+F)
// zoff<0 -> plain mean (L1 pre-agg). TPB*W == F.
template <int F, int TPB, int W>
__global__ __launch_bounds__(TPB)
void gs_agg_post(const unsigned short* __restrict__ C, int ldc, int zoff,
                 const int* __restrict__ rp, const int* __restrict__ col,
                 const float* __restrict__ bias,
                 unsigned short* __restrict__ hout, float* __restrict__ fout, int relu) {
  static_assert(TPB * W == F, "layout");
  const int v = blockIdx.x;
  const int tid = threadIdx.x;
  const int s0 = rp[v], s1 = rp[v + 1];
  const float inv = 1.0f / (float)max(s1 - s0, 1);
  float acc[W];
#pragma unroll
  for (int w = 0; w < W; ++w) acc[w] = 0.f;

  __shared__ int nb[TPB];
  for (int base = s0; base < s1; base += TPB) {
    int m = min(s1 - base, TPB);
    __syncthreads();
    if (tid < m) nb[tid] = col[base + tid];
    __syncthreads();
    int j = 0;
    // 4x unrolled: 4 independent gather loads in flight per lane
    for (; j + 4 <= m; j += 4) {
      const unsigned short* x0 = C + (size_t)nb[j + 0] * ldc + tid * W;
      const unsigned short* x1 = C + (size_t)nb[j + 1] * ldc + tid * W;
      const unsigned short* x2 = C + (size_t)nb[j + 2] * ldc + tid * W;
      const unsigned short* x3 = C + (size_t)nb[j + 3] * ldc + tid * W;
      if constexpr (W == 4) {
        ushort4 u0 = *(const ushort4*)x0;
        ushort4 u1 = *(const ushort4*)x1;
        ushort4 u2 = *(const ushort4*)x2;
        ushort4 u3 = *(const ushort4*)x3;
        acc[0] += bf2f(u0.x) + bf2f(u1.x) + bf2f(u2.x) + bf2f(u3.x);
        acc[1] += bf2f(u0.y) + bf2f(u1.y) + bf2f(u2.y) + bf2f(u3.y);
        acc[2] += bf2f(u0.z) + bf2f(u1.z) + bf2f(u2.z) + bf2f(u3.z);
        acc[3] += bf2f(u0.w) + bf2f(u1.w) + bf2f(u2.w) + bf2f(u3.w);
      } else {
        ushort2 u0 = *(const ushort2*)x0;
        ushort2 u1 = *(const ushort2*)x1;
        ushort2 u2 = *(const ushort2*)x2;
        ushort2 u3 = *(const ushort2*)x3;
        acc[0] += bf2f(u0.x) + bf2f(u1.x) + bf2f(u2.x) + bf2f(u3.x);
        acc[1] += bf2f(u0.y) + bf2f(u1.y) + bf2f(u2.y) + bf2f(u3.y);
      }
    }
    for (; j < m; ++j) {
      const unsigned short* xr = C + (size_t)nb[j] * ldc + tid * W;
      if constexpr (W == 4) {
        ushort4 u = *(const ushort4*)xr;
        acc[0] += bf2f(u.x); acc[1] += bf2f(u.y); acc[2] += bf2f(u.z); acc[3] += bf2f(u.w);
      } else {
        ushort2 u = *(const ushort2*)xr;
        acc[0] += bf2f(u.x); acc[1] += bf2f(u.y);
      }
    }
  }

  float o[W];
#pragma unroll
  for (int w = 0; w < W; ++w) o[w] = acc[w] * inv;
  if (zoff >= 0) {
    const unsigned short* zr = C + (size_t)v * ldc + zoff + tid * W;
    if constexpr (W == 4) {
      ushort4 u = *(const ushort4*)zr;
      o[0] += bf2f(u.x); o[1] += bf2f(u.y); o[2] += bf2f(u.z); o[3] += bf2f(u.w);
    } else {
      ushort2 u = *(const ushort2*)zr;
      o[0] += bf2f(u.x); o[1] += bf2f(u.y);
    }
  }
  if (bias) {
#pragma unroll
    for (int w = 0; w < W; ++w) o[w] += bias[tid * W + w];
  }
  if (relu) {
#pragma unroll
    for (int w = 0; w < W; ++w) o[w] = fmaxf(o[w], 0.f);
  }
  if (hout) {
    if constexpr (W == 4) {
      ushort4 u; u.x = f2bf(o[0]); u.y = f2bf(o[1]); u.z = f2bf(o[2]); u.w = f2bf(o[3]);
      *(ushort4*)(hout + (size_t)v * F + tid * W) = u;
    } else {
      ushort2 u; u.x = f2bf(o[0]); u.y = f2bf(o[1]);
      *(ushort2*)(hout + (size_t)v * F + tid * W) = u;
    }
  }
  if (fout) {
    if constexpr (W == 4) {
      *(float4*)(fout + (size_t)v * F + tid * W) = make_float4(o[0], o[1], o[2], o[3]);
    } else {
      *(float2*)(fout + (size_t)v * F + tid * W) = make_float2(o[0], o[1]);
    }
  }
}

// ---------------- GEMM: C = act(A1@B1^T [+ A2@B2^T] + bias) ----------------
// A row-major M x K (bf16), B TRANSPOSED: Nn x K row-major (bf16).
// 128x128 tile, BK=64, 4 waves of 4x4 16x16x32 MFMA (2 K-steps per iter).
// XOR chunk swizzle: 16B chunk c of row r stored at c^(r&7) -> fragment
// ds_read_b128 is 2 lanes/bank (free). Nn%128==0, K%64==0.
// 1-D grid swizzled: groups of MG M-tiles sweep all N-tiles (A stays L2-hot).
__global__ __launch_bounds__(256)
void gs_gemm(const unsigned short* __restrict__ A1, const unsigned short* __restrict__ A2,
             const unsigned short* __restrict__ B1, const unsigned short* __restrict__ B2,
             const float* __restrict__ bias, unsigned short* __restrict__ Hout,
             int M, int Nn, int K, int doRelu, int Mt, int Nt) {
  __shared__ unsigned short lA[128 * 64];
  __shared__ unsigned short lB[128 * 64];
  const int tid = threadIdx.x;
  const int wid = tid >> 6;
  const int lane = tid & 63;

  const int MG = 8;
  const int per = MG * Nt;
  const int g = blockIdx.x / per;
  const int rem = blockIdx.x - g * per;
  const int gsz = min(MG, Mt - g * MG);
  const int nIdx = rem / gsz;
  const int mIdx = g * MG + (rem - nIdx * gsz);
  const int bM = mIdx * 128;
  const int bN = nIdx * 128;
  const int wM = (wid >> 1) * 64;
  const int wN = (wid & 1) * 64;

  f32x4 acc[4][4];
#pragma unroll
  for (int i = 0; i < 4; ++i)
#pragma unroll
    for (int j = 0; j < 4; ++j) acc[i][j] = (f32x4){0.f, 0.f, 0.f, 0.f};

  const int mrow = wM + (lane & 15);
  const int nrow = wN + (lane & 15);
  const int q = lane >> 4;            // quad (k-offset within 32-K slice)
  const int swz = lane & 7;           // read-side swizzle key (== row&7 of frag row)
  const int srow = wid * 8 + (lane >> 3);        // staging row within 32-row band
  const int sc = (lane & 7) ^ (lane >> 3);       // fetched chunk (XOR swizzle)
  const int npass = A2 ? 2 : 1;

  for (int pass = 0; pass < npass; ++pass) {
    const unsigned short* Ap = pass ? A2 : A1;
    const unsigned short* Bp = pass ? B2 : B1;
    for (int k0 = 0; k0 < K; k0 += 64) {
#pragma unroll
      for (int r = 0; r < 4; ++r) {
        int row = r * 32 + srow;
        int ga = bM + row;
        if (ga >= M) ga = M - 1;                  // clamp: OOB rows never stored
        const unsigned short* gpA = Ap + (size_t)ga * K + k0 + sc * 8;
        const unsigned short* gpB = Bp + (size_t)(bN + row) * K + k0 + sc * 8;
        unsigned lo = (unsigned)(r * 32 + wid * 8) * 128;  // wave-uniform byte base
        __builtin_amdgcn_global_load_lds(
            (const __attribute__((address_space(1))) unsigned int*)gpA,
            (__attribute__((address_space(3))) unsigned int*)((char*)lA + lo), 16, 0, 0);
        __builtin_amdgcn_global_load_lds(
            (const __attribute__((address_space(1))) unsigned int*)gpB,
            (__attribute__((address_space(3))) unsigned int*)((char*)lB + lo), 16, 0, 0);
      }
      __syncthreads();
#pragma unroll
      for (int s = 0; s < 2; ++s) {
        const int cofs = ((s * 4 + q) ^ swz) * 8;
        short8 aF[4], bF[4];
#pragma unroll
        for (int i = 0; i < 4; ++i) {
          aF[i] = *(const short8*)&lA[(mrow + i * 16) * 64 + cofs];
          bF[i] = *(const short8*)&lB[(nrow + i * 16) * 64 + cofs];
        }
#pragma unroll
        for (int i = 0; i < 4; ++i)
#pragma unroll
          for (int j = 0; j < 4; ++j)
            acc[i][j] = __builtin_amdgcn_mfma_f32_16x16x32_bf16(aF[i], bF[j], acc[i][j], 0, 0, 0);
      }
      __syncthreads();
    }
  }

  // C/D layout: col = lane&15, row = (lane>>4)*4 + reg   [m89/m91]
  const int rbase = bM + wM + (lane >> 4) * 4;
#pragma unroll
  for (int i = 0; i < 4; ++i) {
#pragma unroll
    for (int r = 0; r < 4; ++r) {
      int row = rbase + i * 16 + r;
      if (row >= M) continue;
#pragma unroll
      for (int j = 0; j < 4; ++j) {
        int colN = bN + wN + j * 16 + (lane & 15);
        float v = acc[i][j][r];
        if (bias) v += bias[colN];
        if (doRelu) v = fmaxf(v, 0.f);
        Hout[(size_t)row * Nn + colN] = f2bf(v);
      }
    }
  }
}

// ---------------- layer 5 ----------------
// yz[v, 0:5] = h4[v]@Wl5, yz[v, 5:10] = h4[v]@Wr5   (fp32)
__global__ __launch_bounds__(64)
void gs_l5dot(const unsigned short* __restrict__ h4, const float* __restrict__ Wl,
              const float* __restrict__ Wr, float* __restrict__ yz) {
  __shared__ float sW[2560];
  const int v = blockIdx.x;
  const int l = threadIdx.x;
  for (int i = l; i < 2560; i += 64) sW[i] = (i < 1280) ? Wl[i] : Wr[i - 1280];
  __syncthreads();
  ushort4 u = ((const ushort4*)(h4 + (size_t)v * 256))[l];   // k = 4l..4l+3
  float hv[4] = {bf2f(u.x), bf2f(u.y), bf2f(u.z), bf2f(u.w)};
  float acc[10];
#pragma unroll
  for (int n = 0; n < 10; ++n) acc[n] = 0.f;
#pragma unroll
  for (int t = 0; t < 4; ++t) {
    int k = 4 * l + t;
#pragma unroll
    for (int n = 0; n < 5; ++n) {
      acc[n] += hv[t] * sW[k * 5 + n];
      acc[5 + n] += hv[t] * sW[1280 + k * 5 + n];
    }
  }
#pragma unroll
  for (int n = 0; n < 10; ++n)
    for (int off = 32; off > 0; off >>= 1) acc[n] += __shfl_down(acc[n], off, 64);
  if (l == 0) {
#pragma unroll
    for (int n = 0; n < 10; ++n) yz[(size_t)v * 10 + n] = acc[n];
  }
}

// out[v] = mean_{nb} y5[nb] + z5[v] + b  (no relu)
__global__ __launch_bounds__(64)
void gs_l5agg(const float* __restrict__ yz, const int* __restrict__ rp,
              const int* __restrict__ col, const float* __restrict__ b,
              float* __restrict__ out) {
  const int v = blockIdx.x;
  const int l = threadIdx.x;
  const int s0 = rp[v], s1 = rp[v + 1];
  const float inv = 1.0f / (float)max(s1 - s0, 1);
  float acc[5] = {0.f, 0.f, 0.f, 0.f, 0.f};
  for (int e = s0 + l; e < s1; e += 64) {
    const float* yr = yz + (size_t)col[e] * 10;
#pragma unroll
    for (int n = 0; n < 5; ++n) acc[n] += yr[n];
  }
#pragma unroll
  for (int n = 0; n < 5; ++n)
    for (int off = 32; off > 0; off >>= 1) acc[n] += __shfl_down(acc[n], off, 64);
  if (l == 0) {
#pragma unroll
    for (int n = 0; n < 5; ++n)
      out[(size_t)v * 5 + n] = acc[n] * inv + yz[(size_t)v * 10 + 5 + n] + b[n];
  }
}

// ---------------- launcher ----------------
extern "C" void kernel_launch(void* const* d_in, const int* in_sizes, int n_in,
                              void* d_out, int out_size, void* d_ws, size_t ws_size,
                              hipStream_t stream) {
  const float* x = (const float*)d_in[0];
  const int* ei = (const int*)d_in[1];
  const int N = in_sizes[0] / 768;
  const int E = in_sizes[1] / 2;
  const int* src = ei;
  const int* dst = ei + E;

  const float* Wl[5];
  const float* Wr[5];
  const float* bb[5];
  for (int l = 0; l < 5; ++l) {
    Wl[l] = (const float*)d_in[2 + 3 * l];
    Wr[l] = (const float*)d_in[3 + 3 * l];
    bb[l] = (const float*)d_in[4 + 3 * l];
  }

  char* w = (char*)d_ws;
  size_t off = 0;
  auto take = [&](size_t bytes) -> char* {
    char* p = w + off;
    off = (off + bytes + 255) & ~(size_t)255;
    return p;
  };
  // arenas (aliased over layer lifetime)
  unsigned short* ar1 = (unsigned short*)take((size_t)N * 768 * 2);   // xb -> C3
  unsigned short* ar2 = (unsigned short*)take((size_t)N * 768 * 2);   // aggb -> h2
  unsigned short* ar3 = (unsigned short*)take((size_t)N * 1536 * 2);  // h1 -> C4|h3|h4|yz5
  unsigned short* C2  = (unsigned short*)take((size_t)N * 1536 * 2);
  int* cnt  = (int*)take((size_t)N * 4);
  int* rp   = (int*)take((size_t)(N + 1) * 4);
  int* cur  = (int*)take((size_t)N * 4);
  int* col  = (int*)take((size_t)E * 4);
  const int nbChunks = (N + 1023) / 1024;
  int* bsum = (int*)take((size_t)(nbChunks + 1) * 4);
  unsigned short* WT1l = (unsigned short*)take((size_t)1536 * 768 * 2);
  unsigned short* WT1r = (unsigned short*)take((size_t)1536 * 768 * 2);
  unsigned short* WT2  = (unsigned short*)take((size_t)1536 * 1536 * 2);
  unsigned short* WT3  = (unsigned short*)take((size_t)768 * 768 * 2);
  unsigned short* WT4  = (unsigned short*)take((size_t)512 * 384 * 2);

  unsigned short* xb   = ar1;
  unsigned short* C3   = ar1;
  unsigned short* aggb = ar2;
  unsigned short* h2   = ar2;
  unsigned short* h1   = ar3;
  unsigned short* C4   = ar3;                                  // N x 512
  unsigned short* h3   = ar3 + (size_t)N * 512;                // N x 384
  unsigned short* h4   = ar3 + (size_t)N * (512 + 384);        // N x 256
  float*          yz5  = (float*)(ar3 + (size_t)N * (512 + 384 + 256)); // N x 10 f32

  const int M = N;
  const int Mt = (M + 127) / 128;

  // CSR build
  gs_zero_i32<<<(N + 255) / 256, 256, 0, stream>>>(cnt, N);
  gs_count_deg<<<(E + 255) / 256, 256, 0, stream>>>(dst, cnt, E);
  gs_scanA<<<nbChunks, 256, 0, stream>>>(cnt, rp, bsum, N);
  gs_scanB<<<1, 64, 0, stream>>>(bsum, nbChunks);
  gs_scanC<<<(N + 256) / 256, 256, 0, stream>>>(rp, cur, bsum, N, nbChunks);
  gs_fill_csr<<<(E + 255) / 256, 256, 0, stream>>>(src, dst, cur, col, E);

  // conversions (all coalesced)
  gs_f32_to_bf16<<<((N * 768 / 4) + 255) / 256, 256, 0, stream>>>(x, xb, N * 768 / 4);
  gs_tpack<<<dim3(24, 48), dim3(32, 8), 0, stream>>>(Wl[0], WT1l, 768, 1536);
  gs_tpack<<<dim3(24, 48), dim3(32, 8), 0, stream>>>(Wr[0], WT1r, 768, 1536);
  gs_tpack<<<dim3(48, 24), dim3(32, 8), 0, stream>>>(Wl[1], WT2, 1536, 768);
  gs_tpack<<<dim3(48, 24), dim3(32, 8), 0, stream>>>(Wr[1], WT2 + (size_t)768 * 1536, 1536, 768);
  gs_tpack<<<dim3(24, 12), dim3(32, 8), 0, stream>>>(Wl[2], WT3, 768, 384);
  gs_tpack<<<dim3(24, 12), dim3(32, 8), 0, stream>>>(Wr[2], WT3 + (size_t)384 * 768, 768, 384);
  gs_tpack<<<dim3(12, 8), dim3(32, 8), 0, stream>>>(Wl[3], WT4, 384, 256);
  gs_tpack<<<dim3(12, 8), dim3(32, 8), 0, stream>>>(Wr[3], WT4 + (size_t)256 * 384, 384, 256);

  float* houtF = (float*)d_out;                 // [N,256] fp32
  float* out5  = (float*)d_out + (size_t)N * 256;

  // L1: agg-before (Fin 768 < Fout 1536), dual GEMM -> h1 (relu+bias)
  gs_agg_post<768, 192, 4><<<N, 192, 0, stream>>>(xb, 768, -1, rp, col, nullptr, aggb, nullptr, 0);
  gs_gemm<<<Mt * 12, 256, 0, stream>>>(aggb, xb, WT1l, WT1r, bb[0], h1, M, 1536, 768, 1, Mt, 12);

  // L2: GEMM C2 = h1 @ [Wl2|Wr2]  (N x 1536), fused agg over 768 -> h2
  gs_gemm<<<Mt * 12, 256, 0, stream>>>(h1, nullptr, WT2, nullptr, nullptr, C2, M, 1536, 1536, 0, Mt, 12);
  gs_agg_post<768, 192, 4><<<N, 192, 0, stream>>>(C2, 1536, 768, rp, col, bb[1], h2, nullptr, 1);

  // L3: GEMM C3 = h2 @ [Wl3|Wr3]  (N x 768), fused agg over 384 -> h3
  gs_gemm<<<Mt * 6, 256, 0, stream>>>(h2, nullptr, WT3, nullptr, nullptr, C3, M, 768, 768, 0, Mt, 6);
  gs_agg_post<384, 192, 2><<<N, 192, 0, stream>>>(C3, 768, 384, rp, col, bb[2], h3, nullptr, 1);

  // L4: GEMM C4 = h3 @ [Wl4|Wr4]  (N x 512), fused agg over 256 -> h4 (bf16) + d_out (fp32)
  gs_gemm<<<Mt * 4, 256, 0, stream>>>(h3, nullptr, WT4, nullptr, nullptr, C4, M, 512, 384, 0, Mt, 4);
  gs_agg_post<256, 64, 4><<<N, 64, 0, stream>>>(C4, 512, 256, rp, col, bb[3], h4, houtF, 1);

  // L5: per-node dot -> yz5 [N,10] fp32, then tiny agg over 5 -> out
  gs_l5dot<<<N, 64, 0, stream>>>(h4, Wl[4], Wr[4], yz5);
  gs_l5agg<<<N, 64, 0, stream>>>(yz5, rp, col, bb[4], out5);
}

// Round 4
// 687.108 us; speedup vs baseline: 1.6266x; 1.0582x over previous
//
#include <hip/hip_runtime.h>
#include <stdint.h>

typedef __attribute__((ext_vector_type(8))) short short8;
typedef __attribute__((ext_vector_type(4))) float f32x4;

__device__ __forceinline__ float bf2f(unsigned short s) {
  return __uint_as_float(((unsigned)s) << 16);
}
__device__ __forceinline__ unsigned short f2bf(float f) {
  unsigned u = __float_as_uint(f);
  u += 0x7fffu + ((u >> 16) & 1u);   // round-to-nearest-even
  return (unsigned short)(u >> 16);
}

// ---------------- CSR build ----------------
__global__ void gs_count_deg(const int* __restrict__ dst, int* __restrict__ cnt, int E) {
  int e = blockIdx.x * 256 + threadIdx.x;
  if (e < E) atomicAdd(&cnt[dst[e]], 1);
}

// 3-phase scan: A) per-1024-chunk local exclusive scan + chunk sum
__global__ void gs_scanA(const int* __restrict__ cnt, int* __restrict__ rp,
                         int* __restrict__ bsum, int n) {
  __shared__ int sm[256];
  const int b = blockIdx.x, t = threadIdx.x;
  const int base = b * 1024 + t * 4;
  int v[4]; int s = 0;
#pragma unroll
  for (int i = 0; i < 4; ++i) { v[i] = (base + i < n) ? cnt[base + i] : 0; s += v[i]; }
  sm[t] = s;
  __syncthreads();
  for (int off = 1; off < 256; off <<= 1) {
    int x = (t >= off) ? sm[t - off] : 0;
    __syncthreads();
    sm[t] += x;
    __syncthreads();
  }
  int run = sm[t] - s;
#pragma unroll
  for (int i = 0; i < 4; ++i) { if (base + i < n) rp[base + i] = run; run += v[i]; }
  if (t == 255) bsum[b] = sm[255];
}

// B) serial scan of chunk sums (~20 entries), total stored at bsum[nb]
__global__ void gs_scanB(int* bsum, int nb) {
  if (threadIdx.x == 0 && blockIdx.x == 0) {
    int run = 0;
    for (int i = 0; i < nb; ++i) { int v = bsum[i]; bsum[i] = run; run += v; }
    bsum[nb] = run;
  }
}

// C) add chunk offsets, replicate into cur, set rp[n]
__global__ void gs_scanC(int* __restrict__ rp, int* __restrict__ cur,
                         const int* __restrict__ bsum, int n, int nb) {
  int i = blockIdx.x * 256 + threadIdx.x;
  if (i < n) {
    int v = rp[i] + bsum[i >> 10];
    rp[i] = v;
    cur[i] = v;
  }
  if (i == n) rp[n] = bsum[nb];
}

__global__ void gs_fill_csr(const int* __restrict__ src, const int* __restrict__ dst,
                            int* __restrict__ cur, int* __restrict__ col, int E) {
  int e = blockIdx.x * 256 + threadIdx.x;
  if (e < E) {
    int pos = atomicAdd(&cur[dst[e]], 1);
    col[pos] = src[e];
  }
}

// ---------------- conversions / weight packing ----------------
__global__ void gs_f32_to_bf16(const float* __restrict__ in, unsigned short* __restrict__ out, int n4) {
  int i = blockIdx.x * 256 + threadIdx.x;
  if (i < n4) {
    float4 f = ((const float4*)in)[i];
    ushort4 o;
    o.x = f2bf(f.x); o.y = f2bf(f.y); o.z = f2bf(f.z); o.w = f2bf(f.w);
    ((ushort4*)out)[i] = o;
  }
}

// batched tiled transpose-pack: W [K x F] fp32 row-major -> WT [F x K] bf16 row-major
struct TP { const float* W; unsigned short* WT; int K, F; };
struct TP8 { TP t[8]; };

__global__ void gs_tpack8(TP8 args) {
  const TP a = args.t[blockIdx.z];
  const int k0 = blockIdx.x * 32, f0 = blockIdx.y * 32;
  if (k0 >= a.K || f0 >= a.F) return;
  __shared__ float t[32][33];
  const int tx = threadIdx.x, ty = threadIdx.y;
#pragma unroll
  for (int r = ty; r < 32; r += 8) {
    int k = k0 + r, f = f0 + tx;
    t[r][tx] = (k < a.K && f < a.F) ? a.W[(size_t)k * a.F + f] : 0.f;
  }
  __syncthreads();
#pragma unroll
  for (int r = ty; r < 32; r += 8) {
    int f = f0 + r, k = k0 + tx;
    if (f < a.F && k < a.K) a.WT[(size_t)f * a.K + k] = f2bf(t[tx][r]);
  }
}

// ---------------- sliced fused aggregation ----------------
// block = (node v, 128-col slice). 64 threads, ushort2/lane (256 B row footprint).
// Slice-major dispatch keeps the co-resident gather footprint ~N*256B (~5 MB)
// so the deg/8 per-XCD reuse lands in L2 instead of L3.
// o = mean_{nb} C[nb, c0:c0+128] (+ C[v, zoff+c0 ...] if zoff>=0) (+bias) (relu?)
__global__ __launch_bounds__(64)
void gs_agg_slice(const unsigned short* __restrict__ C, int ldc, int zoff,
                  const int* __restrict__ rp, const int* __restrict__ col,
                  const float* __restrict__ bias,
                  unsigned short* __restrict__ hout, float* __restrict__ fout,
                  int F, int relu) {
  const int v = blockIdx.x;
  const int cc = blockIdx.y * 128 + 2 * threadIdx.x;
  const int l = threadIdx.x;
  const int s0 = rp[v], s1 = rp[v + 1];
  const float inv = 1.0f / (float)max(s1 - s0, 1);
  float a0 = 0.f, a1 = 0.f;
  __shared__ int nb[64];
  for (int base = s0; base < s1; base += 64) {
    int m = min(s1 - base, 64);
    __syncthreads();
    if (l < m) nb[l] = col[base + l];
    __syncthreads();
    int j = 0;
    for (; j + 4 <= m; j += 4) {
      ushort2 u0 = *(const ushort2*)(C + (size_t)nb[j + 0] * ldc + cc);
      ushort2 u1 = *(const ushort2*)(C + (size_t)nb[j + 1] * ldc + cc);
      ushort2 u2 = *(const ushort2*)(C + (size_t)nb[j + 2] * ldc + cc);
      ushort2 u3 = *(const ushort2*)(C + (size_t)nb[j + 3] * ldc + cc);
      a0 += bf2f(u0.x) + bf2f(u1.x) + bf2f(u2.x) + bf2f(u3.x);
      a1 += bf2f(u0.y) + bf2f(u1.y) + bf2f(u2.y) + bf2f(u3.y);
    }
    for (; j < m; ++j) {
      ushort2 u = *(const ushort2*)(C + (size_t)nb[j] * ldc + cc);
      a0 += bf2f(u.x); a1 += bf2f(u.y);
    }
  }
  float o0 = a0 * inv, o1 = a1 * inv;
  if (zoff >= 0) {
    ushort2 u = *(const ushort2*)(C + (size_t)v * ldc + zoff + cc);
    o0 += bf2f(u.x); o1 += bf2f(u.y);
  }
  if (bias) { o0 += bias[cc]; o1 += bias[cc + 1]; }
  if (relu) { o0 = fmaxf(o0, 0.f); o1 = fmaxf(o1, 0.f); }
  if (hout) {
    ushort2 u; u.x = f2bf(o0); u.y = f2bf(o1);
    *(ushort2*)(hout + (size_t)v * F + cc) = u;
  }
  if (fout) *(float2*)(fout + (size_t)v * F + cc) = make_float2(o0, o1);
}

// ---------------- GEMM: C = act(A1@B1^T [+ A2@B2^T] + bias) ----------------
// A row-major M x K (bf16), B TRANSPOSED: Nn x K row-major (bf16).
// 128x128 tile, BK=64, 4 waves of 4x4 16x16x32 MFMA (2 K-steps per iter).
// XOR chunk swizzle -> conflict-free ds_read_b128. Nn%128==0, K%64==0.
// 1-D grid swizzled: groups of MG M-tiles sweep all N-tiles (A stays L2-hot).
__global__ __launch_bounds__(256)
void gs_gemm(const unsigned short* __restrict__ A1, const unsigned short* __restrict__ A2,
             const unsigned short* __restrict__ B1, const unsigned short* __restrict__ B2,
             const float* __restrict__ bias, unsigned short* __restrict__ Hout,
             int M, int Nn, int K, int doRelu, int Mt, int Nt) {
  __shared__ unsigned short lA[128 * 64];
  __shared__ unsigned short lB[128 * 64];
  const int tid = threadIdx.x;
  const int wid = tid >> 6;
  const int lane = tid & 63;

  const int MG = 8;
  const int per = MG * Nt;
  const int g = blockIdx.x / per;
  const int rem = blockIdx.x - g * per;
  const int gsz = min(MG, Mt - g * MG);
  const int nIdx = rem / gsz;
  const int mIdx = g * MG + (rem - nIdx * gsz);
  const int bM = mIdx * 128;
  const int bN = nIdx * 128;
  const int wM = (wid >> 1) * 64;
  const int wN = (wid & 1) * 64;

  f32x4 acc[4][4];
#pragma unroll
  for (int i = 0; i < 4; ++i)
#pragma unroll
    for (int j = 0; j < 4; ++j) acc[i][j] = (f32x4){0.f, 0.f, 0.f, 0.f};

  const int mrow = wM + (lane & 15);
  const int nrow = wN + (lane & 15);
  const int q = lane >> 4;            // quad (k-offset within 32-K slice)
  const int swz = lane & 7;           // read-side swizzle key (== row&7 of frag row)
  const int srow = wid * 8 + (lane >> 3);        // staging row within 32-row band
  const int sc = (lane & 7) ^ (lane >> 3);       // fetched chunk (XOR swizzle)
  const int npass = A2 ? 2 : 1;

  for (int pass = 0; pass < npass; ++pass) {
    const unsigned short* Ap = pass ? A2 : A1;
    const unsigned short* Bp = pass ? B2 : B1;
    for (int k0 = 0; k0 < K; k0 += 64) {
#pragma unroll
      for (int r = 0; r < 4; ++r) {
        int row = r * 32 + srow;
        int ga = bM + row;
        if (ga >= M) ga = M - 1;                  // clamp: OOB rows never stored
        const unsigned short* gpA = Ap + (size_t)ga * K + k0 + sc * 8;
        const unsigned short* gpB = Bp + (size_t)(bN + row) * K + k0 + sc * 8;
        unsigned lo = (unsigned)(r * 32 + wid * 8) * 128;  // wave-uniform byte base
        __builtin_amdgcn_global_load_lds(
            (const __attribute__((address_space(1))) unsigned int*)gpA,
            (__attribute__((address_space(3))) unsigned int*)((char*)lA + lo), 16, 0, 0);
        __builtin_amdgcn_global_load_lds(
            (const __attribute__((address_space(1))) unsigned int*)gpB,
            (__attribute__((address_space(3))) unsigned int*)((char*)lB + lo), 16, 0, 0);
      }
      __syncthreads();
#pragma unroll
      for (int s = 0; s < 2; ++s) {
        const int cofs = ((s * 4 + q) ^ swz) * 8;
        short8 aF[4], bF[4];
#pragma unroll
        for (int i = 0; i < 4; ++i) {
          aF[i] = *(const short8*)&lA[(mrow + i * 16) * 64 + cofs];
          bF[i] = *(const short8*)&lB[(nrow + i * 16) * 64 + cofs];
        }
#pragma unroll
        for (int i = 0; i < 4; ++i)
#pragma unroll
          for (int j = 0; j < 4; ++j)
            acc[i][j] = __builtin_amdgcn_mfma_f32_16x16x32_bf16(aF[i], bF[j], acc[i][j], 0, 0, 0);
      }
      __syncthreads();
    }
  }

  // C/D layout: col = lane&15, row = (lane>>4)*4 + reg   [m89/m91]
  const int rbase = bM + wM + (lane >> 4) * 4;
#pragma unroll
  for (int i = 0; i < 4; ++i) {
#pragma unroll
    for (int r = 0; r < 4; ++r) {
      int row = rbase + i * 16 + r;
      if (row >= M) continue;
#pragma unroll
      for (int j = 0; j < 4; ++j) {
        int colN = bN + wN + j * 16 + (lane & 15);
        float v = acc[i][j][r];
        if (bias) v += bias[colN];
        if (doRelu) v = fmaxf(v, 0.f);
        Hout[(size_t)row * Nn + colN] = f2bf(v);
      }
    }
  }
}

// ---------------- layer 5 ----------------
// yz[v, 0:5] = h4[v]@Wl5, yz[v, 5:10] = h4[v]@Wr5   (fp32)
__global__ __launch_bounds__(64)
void gs_l5dot(const unsigned short* __restrict__ h4, const float* __restrict__ Wl,
              const float* __restrict__ Wr, float* __restrict__ yz) {
  __shared__ float sW[2560];
  const int v = blockIdx.x;
  const int l = threadIdx.x;
  for (int i = l; i < 2560; i += 64) sW[i] = (i < 1280) ? Wl[i] : Wr[i - 1280];
  __syncthreads();
  ushort4 u = ((const ushort4*)(h4 + (size_t)v * 256))[l];   // k = 4l..4l+3
  float hv[4] = {bf2f(u.x), bf2f(u.y), bf2f(u.z), bf2f(u.w)};
  float acc[10];
#pragma unroll
  for (int n = 0; n < 10; ++n) acc[n] = 0.f;
#pragma unroll
  for (int t = 0; t < 4; ++t) {
    int k = 4 * l + t;
#pragma unroll
    for (int n = 0; n < 5; ++n) {
      acc[n] += hv[t] * sW[k * 5 + n];
      acc[5 + n] += hv[t] * sW[1280 + k * 5 + n];
    }
  }
#pragma unroll
  for (int n = 0; n < 10; ++n)
    for (int off = 32; off > 0; off >>= 1) acc[n] += __shfl_down(acc[n], off, 64);
  if (l == 0) {
#pragma unroll
    for (int n = 0; n < 10; ++n) yz[(size_t)v * 10 + n] = acc[n];
  }
}

// out[v] = mean_{nb} y5[nb] + z5[v] + b  (no relu)
__global__ __launch_bounds__(64)
void gs_l5agg(const float* __restrict__ yz, const int* __restrict__ rp,
              const int* __restrict__ col, const float* __restrict__ b,
              float* __restrict__ out) {
  const int v = blockIdx.x;
  const int l = threadIdx.x;
  const int s0 = rp[v], s1 = rp[v + 1];
  const float inv = 1.0f / (float)max(s1 - s0, 1);
  float acc[5] = {0.f, 0.f, 0.f, 0.f, 0.f};
  for (int e = s0 + l; e < s1; e += 64) {
    const float* yr = yz + (size_t)col[e] * 10;
#pragma unroll
    for (int n = 0; n < 5; ++n) acc[n] += yr[n];
  }
#pragma unroll
  for (int n = 0; n < 5; ++n)
    for (int off = 32; off > 0; off >>= 1) acc[n] += __shfl_down(acc[n], off, 64);
  if (l == 0) {
#pragma unroll
    for (int n = 0; n < 5; ++n)
      out[(size_t)v * 5 + n] = acc[n] * inv + yz[(size_t)v * 10 + 5 + n] + b[n];
  }
}

// ---------------- launcher ----------------
extern "C" void kernel_launch(void* const* d_in, const int* in_sizes, int n_in,
                              void* d_out, int out_size, void* d_ws, size_t ws_size,
                              hipStream_t stream) {
  const float* x = (const float*)d_in[0];
  const int* ei = (const int*)d_in[1];
  const int N = in_sizes[0] / 768;
  const int E = in_sizes[1] / 2;
  const int* src = ei;
  const int* dst = ei + E;

  const float* Wl[5];
  const float* Wr[5];
  const float* bb[5];
  for (int l = 0; l < 5; ++l) {
    Wl[l] = (const float*)d_in[2 + 3 * l];
    Wr[l] = (const float*)d_in[3 + 3 * l];
    bb[l] = (const float*)d_in[4 + 3 * l];
  }

  char* w = (char*)d_ws;
  size_t off = 0;
  auto take = [&](size_t bytes) -> char* {
    char* p = w + off;
    off = (off + bytes + 255) & ~(size_t)255;
    return p;
  };
  // arenas (aliased over layer lifetime)
  unsigned short* ar1 = (unsigned short*)take((size_t)N * 768 * 2);   // xb -> C3
  unsigned short* ar2 = (unsigned short*)take((size_t)N * 768 * 2);   // aggb -> h2
  unsigned short* ar3 = (unsigned short*)take((size_t)N * 1536 * 2);  // h1 -> C4|h3|h4|yz5
  unsigned short* C2  = (unsigned short*)take((size_t)N * 1536 * 2);
  int* cnt  = (int*)take((size_t)N * 4);
  int* rp   = (int*)take((size_t)(N + 1) * 4);
  int* cur  = (int*)take((size_t)N * 4);
  int* col  = (int*)take((size_t)E * 4);
  const int nbChunks = (N + 1023) / 1024;
  int* bsum = (int*)take((size_t)(nbChunks + 1) * 4);
  unsigned short* WT1l = (unsigned short*)take((size_t)1536 * 768 * 2);
  unsigned short* WT1r = (unsigned short*)take((size_t)1536 * 768 * 2);
  unsigned short* WT2  = (unsigned short*)take((size_t)1536 * 1536 * 2);
  unsigned short* WT3  = (unsigned short*)take((size_t)768 * 768 * 2);
  unsigned short* WT4  = (unsigned short*)take((size_t)512 * 384 * 2);

  unsigned short* xb   = ar1;
  unsigned short* C3   = ar1;
  unsigned short* aggb = ar2;
  unsigned short* h2   = ar2;
  unsigned short* h1   = ar3;
  unsigned short* C4   = ar3;                                  // N x 512
  unsigned short* h3   = ar3 + (size_t)N * 512;                // N x 384
  unsigned short* h4   = ar3 + (size_t)N * (512 + 384);        // N x 256
  float*          yz5  = (float*)(ar3 + (size_t)N * (512 + 384 + 256)); // N x 10 f32

  const int M = N;
  const int Mt = (M + 127) / 128;

  // CSR build
  hipMemsetAsync(cnt, 0, (size_t)N * 4, stream);
  gs_count_deg<<<(E + 255) / 256, 256, 0, stream>>>(dst, cnt, E);
  gs_scanA<<<nbChunks, 256, 0, stream>>>(cnt, rp, bsum, N);
  gs_scanB<<<1, 64, 0, stream>>>(bsum, nbChunks);
  gs_scanC<<<(N + 256) / 256, 256, 0, stream>>>(rp, cur, bsum, N, nbChunks);
  gs_fill_csr<<<(E + 255) / 256, 256, 0, stream>>>(src, dst, cur, col, E);

  // conversions (all coalesced); batched transpose-pack (1 launch)
  gs_f32_to_bf16<<<((N * 768 / 4) + 255) / 256, 256, 0, stream>>>(x, xb, N * 768 / 4);
  TP8 tp;
  tp.t[0] = {Wl[0], WT1l, 768, 1536};
  tp.t[1] = {Wr[0], WT1r, 768, 1536};
  tp.t[2] = {Wl[1], WT2, 1536, 768};
  tp.t[3] = {Wr[1], WT2 + (size_t)768 * 1536, 1536, 768};
  tp.t[4] = {Wl[2], WT3, 768, 384};
  tp.t[5] = {Wr[2], WT3 + (size_t)384 * 768, 768, 384};
  tp.t[6] = {Wl[3], WT4, 384, 256};
  tp.t[7] = {Wr[3], WT4 + (size_t)256 * 384, 384, 256};
  gs_tpack8<<<dim3(48, 48, 8), dim3(32, 8), 0, stream>>>(tp);

  float* houtF = (float*)d_out;                 // [N,256] fp32
  float* out5  = (float*)d_out + (size_t)N * 256;

  // L1: agg-before (Fin 768 < Fout 1536), dual GEMM -> h1 (relu+bias)
  gs_agg_slice<<<dim3(N, 6), 64, 0, stream>>>(xb, 768, -1, rp, col, nullptr, aggb, nullptr, 768, 0);
  gs_gemm<<<Mt * 12, 256, 0, stream>>>(aggb, xb, WT1l, WT1r, bb[0], h1, M, 1536, 768, 1, Mt, 12);

  // L2: GEMM C2 = h1 @ [Wl2|Wr2]  (N x 1536), fused sliced agg over 768 -> h2
  gs_gemm<<<Mt * 12, 256, 0, stream>>>(h1, nullptr, WT2, nullptr, nullptr, C2, M, 1536, 1536, 0, Mt, 12);
  gs_agg_slice<<<dim3(N, 6), 64, 0, stream>>>(C2, 1536, 768, rp, col, bb[1], h2, nullptr, 768, 1);

  // L3: GEMM C3 = h2 @ [Wl3|Wr3]  (N x 768), fused sliced agg over 384 -> h3
  gs_gemm<<<Mt * 6, 256, 0, stream>>>(h2, nullptr, WT3, nullptr, nullptr, C3, M, 768, 768, 0, Mt, 6);
  gs_agg_slice<<<dim3(N, 3), 64, 0, stream>>>(C3, 768, 384, rp, col, bb[2], h3, nullptr, 384, 1);

  // L4: GEMM C4 = h3 @ [Wl4|Wr4]  (N x 512), fused sliced agg over 256 -> h4 (bf16) + d_out (fp32)
  gs_gemm<<<Mt * 4, 256, 0, stream>>>(h3, nullptr, WT4, nullptr, nullptr, C4, M, 512, 384, 0, Mt, 4);
  gs_agg_slice<<<dim3(N, 2), 64, 0, stream>>>(C4, 512, 256, rp, col, bb[3], h4, houtF, 256, 1);

  // L5: per-node dot -> yz5 [N,10] fp32, then tiny agg over 5 -> out
  gs_l5dot<<<N, 64, 0, stream>>>(h4, Wl[4], Wr[4], yz5);
  gs_l5agg<<<N, 64, 0, stream>>>(yz5, rp, col, bb[4], out5);
}